// Round 1
// baseline (5669.390 us; speedup 1.0000x reference)
//
#include <hip/hip_runtime.h>
#include <hip/hip_bf16.h>
#include <math.h>

#define B_  16
#define T_  250
#define E_  512
#define H_  1024
#define V_  32000
#define M_  (B_*T_)     // 4000 token rows
#define H3_ (3*H_)      // 3072

typedef __bf16 bf16;
typedef bf16  bf16x4 __attribute__((ext_vector_type(4)));
typedef bf16  bf16x8 __attribute__((ext_vector_type(8)));
typedef float f32x4  __attribute__((ext_vector_type(4)));

// ---------------- converts ----------------
__global__ void k_cvt(const float* __restrict__ s, bf16* __restrict__ d, int n4) {
    int i = blockIdx.x * blockDim.x + threadIdx.x;
    if (i >= n4) return;
    float4 v = ((const float4*)s)[i];
    bf16x4 o = {(bf16)v.x, (bf16)v.y, (bf16)v.z, (bf16)v.w};
    ((bf16x4*)d)[i] = o;
}

// embedding gather -> bf16 A matrix [4000][512]
__global__ void k_gather(const int* __restrict__ tok, const float* __restrict__ emb,
                         bf16* __restrict__ A) {
    int r = blockIdx.x;            // 0..3999
    int t = tok[r];
    float4 v = ((const float4*)(emb + (size_t)t * E_))[threadIdx.x];   // 128 thr * 4
    bf16x4 o = {(bf16)v.x, (bf16)v.y, (bf16)v.z, (bf16)v.w};
    ((bf16x4*)(A + (size_t)r * E_))[threadIdx.x] = o;
}

// ---------------- GEMM: C[M x N] = A[M x K] * B[K x N] (+bias) ----------------
// MODE 0: bf16 out (x_proj, bias=b0)   MODE 1: f32 out (logits, bias=bo)
// block 256 = 4 waves; tile 64x64, BK=32; wave w does rows w*16..w*16+15 x all 64 cols
template <int MODE>
__global__ __launch_bounds__(256)
void k_gemm(const bf16* __restrict__ A, const bf16* __restrict__ Bm,
            const float* __restrict__ bias, void* __restrict__ Cout,
            int Mtiles, int K, int lda, int ldb, int ldc) {
    const int mt = blockIdx.x % Mtiles;
    const int nt = blockIdx.x / Mtiles;
    const int m0 = mt * 64, n0 = nt * 64;
    __shared__ bf16 sA[64][40];    // [m][k] pad->2-way-free
    __shared__ bf16 sBt[64][40];   // [n][k] (B transposed)
    const int tid  = threadIdx.x;
    const int wave = tid >> 6, lane = tid & 63;
    const int quad = lane >> 4, l16 = lane & 15;
    f32x4 acc[4] = {};

    for (int kk = 0; kk < K; kk += 32) {
        { // stage A: 64 rows x 32 cols, one b128 per thread
            int m = tid >> 2, ch = tid & 3;
            bf16x8 v = {};
            int gm = m0 + m;
            if (gm < M_) v = *(const bf16x8*)(A + (size_t)gm * lda + kk + ch * 8);
            *(bf16x8*)(&sA[m][ch * 8]) = v;
        }
        { // stage B transposed: thread reads B[k][c0..c0+7], writes sBt[c][k]
            int k = tid >> 3, c0 = (tid & 7) * 8;
            bf16x8 v = *(const bf16x8*)(Bm + (size_t)(kk + k) * ldb + n0 + c0);
#pragma unroll
            for (int i = 0; i < 8; i++) sBt[c0 + i][k] = v[i];
        }
        __syncthreads();
        bf16x8 af = *(const bf16x8*)(&sA[wave * 16 + l16][quad * 8]);
#pragma unroll
        for (int nn = 0; nn < 4; nn++) {
            bf16x8 bf_ = *(const bf16x8*)(&sBt[nn * 16 + l16][quad * 8]);
            acc[nn] = __builtin_amdgcn_mfma_f32_16x16x32_bf16(af, bf_, acc[nn], 0, 0, 0);
        }
        __syncthreads();
    }
    // epilogue: D row m = quad*4+reg, col n = l16 (m89-verified layout)
#pragma unroll
    for (int nn = 0; nn < 4; nn++) {
        int n = n0 + nn * 16 + l16;
        float bv = bias[n];
#pragma unroll
        for (int r = 0; r < 4; r++) {
            int m = m0 + wave * 16 + quad * 4 + r;
            if (m < M_) {
                float val = acc[nn][r] + bv;
                if (MODE == 0) ((bf16*)Cout)[(size_t)m * ldc + n] = (bf16)val;
                else           ((float*)Cout)[(size_t)m * ldc + n] = val;
            }
        }
    }
}

// ---------------- GRU recurrence: 64 persistent WGs, grid barrier per step ----------------
#define NWG 64
__global__ __launch_bounds__(256, 1)
void k_gru(const bf16* __restrict__ xproj, const float* __restrict__ U,
           const float* __restrict__ b, const float* __restrict__ h0,
           bf16* __restrict__ hA, bf16* __restrict__ hB,
           bf16* __restrict__ hs, unsigned int* __restrict__ ctr) {
    const int tid  = threadIdx.x;
    const int wave = tid >> 6, lane = tid & 63;
    const int quad = lane >> 4, l16 = lane & 15;
    const int j0 = blockIdx.x * 16;            // this WG owns hidden units j0..j0+15
    __shared__ float sRec[3][16][16];          // [gate][batch][jlocal]

    // Preload U columns for this wave's gate as MFMA B-fragments (128 VGPRs).
    // B-frag: lane holds B[k = s*32 + quad*8 + jj][n = l16]
    bf16x8 uf[32];
    if (wave < 3) {
        const float* Ub = U + (size_t)(wave * H_ + j0 + l16);
#pragma unroll
        for (int s = 0; s < 32; s++) {
#pragma unroll
            for (int jj = 0; jj < 8; jj++) {
                int k = s * 32 + quad * 8 + jj;
                uf[s][jj] = (bf16)Ub[(size_t)k * H3_];
            }
        }
    }

    // Combine-phase identity: one (batch, hidden) pair per thread, state in f32 reg.
    const int cb = tid >> 4;          // batch 0..15
    const int cj = tid & 15;          // hidden offset
    const int j  = j0 + cj;
    const float b1z = b[H3_ + j];
    const float b1r = b[H3_ + H_ + j];
    const float b1h = b[H3_ + 2 * H_ + j];
    float hreg = h0[cb * H_ + j];

    // prefetch x_proj for t=0
    size_t xrow = (size_t)(cb * T_) * H3_;
    float xz = (float)xproj[xrow + j];
    float xr = (float)xproj[xrow + H_ + j];
    float xh = (float)xproj[xrow + 2 * H_ + j];

    for (int t = 0; t < T_; t++) {
        const bf16* hsrc = (t & 1) ? hB : hA;
        bf16*       hdst = (t & 1) ? hA : hB;

        if (wave < 3) {           // rec = h_{t-1} @ U_slice  (one 16x16 tile per gate)
            f32x4 acc = {};
#pragma unroll
            for (int s = 0; s < 32; s++) {
                bf16x8 af = *(const bf16x8*)(hsrc + (size_t)l16 * H_ + s * 32 + quad * 8);
                acc = __builtin_amdgcn_mfma_f32_16x16x32_bf16(af, uf[s], acc, 0, 0, 0);
            }
#pragma unroll
            for (int r = 0; r < 4; r++) sRec[wave][quad * 4 + r][l16] = acc[r];
        }
        __syncthreads();

        // combine: Keras GRUCell reset_after=True
        float rz = sRec[0][cb][cj] + b1z;
        float rr = sRec[1][cb][cj] + b1r;
        float rh = sRec[2][cb][cj] + b1h;
        float az = xz + rz;  az = fminf(fmaxf(az, -30.f), 30.f);
        float ar = xr + rr;  ar = fminf(fmaxf(ar, -30.f), 30.f);
        float z = 1.f / (1.f + __expf(-az));
        float r = 1.f / (1.f + __expf(-ar));
        float ah = xh + r * rh;  ah = fminf(fmaxf(ah, -15.f), 15.f);
        float ex = __expf(2.f * ah);
        float hh = (ex - 1.f) / (ex + 1.f);
        hreg = z * hreg + (1.f - z) * hh;
        bf16 hb = (bf16)hreg;
        hdst[cb * H_ + j] = hb;
        hs[(size_t)(cb * T_ + t) * H_ + j] = hb;

        // prefetch next step's x (latency hides behind the barrier)
        if (t + 1 < T_) {
            size_t xr2 = (size_t)(cb * T_ + t + 1) * H3_;
            xz = (float)xproj[xr2 + j];
            xr = (float)xproj[xr2 + H_ + j];
            xh = (float)xproj[xr2 + 2 * H_ + j];
        }

        // grid barrier: release h writes, arrive, spin, acquire
        __threadfence();
        __syncthreads();
        if (tid == 0) {
            __hip_atomic_fetch_add(ctr, 1u, __ATOMIC_RELEASE, __HIP_MEMORY_SCOPE_AGENT);
            unsigned target = (unsigned)NWG * (t + 1);
            int guard = 0;
            while (__hip_atomic_load(ctr, __ATOMIC_RELAXED, __HIP_MEMORY_SCOPE_AGENT) < target) {
                if (++guard > (1 << 28)) break;   // fail loud (wrong result), not hung
                __builtin_amdgcn_s_sleep(1);
            }
        }
        __syncthreads();
        __threadfence();
    }
}

// ---------------- launch ----------------
extern "C" void kernel_launch(void* const* d_in, const int* in_sizes, int n_in,
                              void* d_out, int out_size, void* d_ws, size_t ws_size,
                              hipStream_t stream) {
    const int*   tok = (const int*)d_in[0];
    const float* h0  = (const float*)d_in[1];
    const float* emb = (const float*)d_in[2];
    const float* W   = (const float*)d_in[3];
    const float* U   = (const float*)d_in[4];
    const float* bb  = (const float*)d_in[5];
    const float* Wo  = (const float*)d_in[6];
    const float* bo  = (const float*)d_in[7];
    float* out = (float*)d_out;

    char* ws = (char*)d_ws;
    bf16* Wo_b  = (bf16*)(ws);                        // 65,536,000 B
    bf16* xproj = (bf16*)(ws + 65536000);             // 24,576,000 B
    bf16* hs    = (bf16*)(ws + 90112000);             //  8,192,000 B
    bf16* Aemb  = (bf16*)(ws + 98304000);             //  4,096,000 B
    bf16* W_b   = (bf16*)(ws + 102400000);            //  3,145,728 B
    bf16* hbufA = (bf16*)(ws + 105545728);            //     32,768 B
    bf16* hbufB = (bf16*)(ws + 105578496);            //     32,768 B
    unsigned* ctr = (unsigned*)(ws + 105611264);      //        256 B

    hipMemsetAsync(ctr, 0, 256, stream);

    // dtype converts / gather
    k_cvt<<<(E_ * H3_ / 4 + 255) / 256, 256, 0, stream>>>(W, W_b, E_ * H3_ / 4);
    k_cvt<<<(H_ * V_ / 4 + 255) / 256, 256, 0, stream>>>(Wo, Wo_b, H_ * V_ / 4);
    k_cvt<<<(B_ * H_ / 4 + 255) / 256, 256, 0, stream>>>(h0, hbufA, B_ * H_ / 4);
    k_gather<<<M_, 128, 0, stream>>>(tok, emb, Aemb);

    // x_proj = emb(x) @ W + b0   [4000 x 3072] bf16
    k_gemm<0><<<63 * (H3_ / 64), 256, 0, stream>>>(Aemb, W_b, bb, xproj,
                                                   63, E_, E_, H3_, H3_);
    // GRU scan
    k_gru<<<NWG, 256, 0, stream>>>(xproj, U, bb, h0, hbufA, hbufB, hs, ctr);

    // logits = hs @ Wo + bo   [4000 x 32000] f32
    k_gemm<1><<<63 * (V_ / 64), 256, 0, stream>>>(hs, Wo_b, bo, out,
                                                  63, H_, H_, V_, V_);
}